// Round 1
// baseline (184.586 us; speedup 1.0000x reference)
//
#include <hip/hip_runtime.h>
#include <hip/hip_bf16.h>

typedef __bf16 bf16_t;
typedef bf16_t bf16x8 __attribute__((ext_vector_type(8)));
typedef float f32x4 __attribute__((ext_vector_type(4)));

#define MFMA16(a, b, c) __builtin_amdgcn_mfma_f32_16x16x32_bf16((a), (b), (c), 0, 0, 0)

// B=8, T=2048, E=1024, H=128
#define TT 2048
#define EE 1024
#define HH 128

// ---------------- prep: Wt[w][n][k] = W[w][k][n], f32 -> bf16 ----------------
__global__ __launch_bounds__(256) void prep_w_kernel(
    const float* __restrict__ Wq, const float* __restrict__ Wk,
    const float* __restrict__ Wv, bf16_t* __restrict__ Wt)
{
    int idx = blockIdx.x * 256 + threadIdx.x;   // 0 .. 3*131072-1
    int w = idx >> 17;
    int r = idx & 131071;                        // n*1024 + k
    int n = r >> 10, k = r & 1023;
    const float* W = (w == 0) ? Wq : (w == 1) ? Wk : Wv;
    Wt[idx] = (bf16_t)W[k * HH + n];
}

// ---------------- QKV GEMM: [16384 x 1024] x [1024 x 128] ----------------
// block 256 thr = 4 waves (2x2 of 64x64), tile 128x128, BK=32
__global__ __launch_bounds__(256) void qkv_kernel(
    const float* __restrict__ x, const bf16_t* __restrict__ Wt,
    bf16_t* __restrict__ Q, bf16_t* __restrict__ Ko, bf16_t* __restrict__ Vt)
{
    __shared__ __attribute__((aligned(16))) bf16_t As[128][40];  // padded rows (80B, 16B-aligned)
    const int row0  = blockIdx.x * 128;
    const int which = blockIdx.y;                 // 0=Q 1=K 2=V
    const bf16_t* Wp = Wt + (size_t)which * (HH * EE);
    const int tid = threadIdx.x;
    const int lane = tid & 63;
    const int wid = tid >> 6;
    const int wm = wid >> 1, wn = wid & 1;
    const int g = lane >> 4, c = lane & 15;

    f32x4 acc[4][4];
    for (int i = 0; i < 4; ++i)
        for (int j = 0; j < 4; ++j) acc[i][j] = (f32x4)0.0f;

    for (int k0 = 0; k0 < EE; k0 += 32) {
        __syncthreads();
        // stage A tile: 128 rows x 32 cols, f32 -> bf16
        for (int j = 0; j < 4; ++j) {
            int s = tid + j * 256;                // float4 slot: 128*8
            int r = s >> 3, c4 = s & 7;
            float4 f = *reinterpret_cast<const float4*>(
                x + (size_t)(row0 + r) * EE + k0 + c4 * 4);
            union { bf16_t h[4]; unsigned long long u; } pk;
            pk.h[0] = (bf16_t)f.x; pk.h[1] = (bf16_t)f.y;
            pk.h[2] = (bf16_t)f.z; pk.h[3] = (bf16_t)f.w;
            *reinterpret_cast<unsigned long long*>(&As[r][c4 * 4]) = pk.u;
        }
        __syncthreads();
        bf16x8 bfr[4];
        for (int nt = 0; nt < 4; ++nt)
            bfr[nt] = *reinterpret_cast<const bf16x8*>(
                Wp + (size_t)(wn * 64 + nt * 16 + c) * EE + k0 + g * 8);
        for (int mt = 0; mt < 4; ++mt) {
            bf16x8 af = *reinterpret_cast<const bf16x8*>(&As[wm * 64 + mt * 16 + c][g * 8]);
            for (int nt = 0; nt < 4; ++nt)
                acc[mt][nt] = MFMA16(af, bfr[nt], acc[mt][nt]);
        }
    }

    if (which == 0) {
        const float sc = 0.08838834764831845f;   // 1/sqrt(128)
        for (int mt = 0; mt < 4; ++mt)
            for (int nt = 0; nt < 4; ++nt) {
                int h  = wn * 64 + nt * 16 + c;
                int t0 = row0 + wm * 64 + mt * 16 + g * 4;
                for (int i = 0; i < 4; ++i)
                    Q[(size_t)(t0 + i) * HH + h] = (bf16_t)(acc[mt][nt][i] * sc);
            }
    } else if (which == 1) {
        for (int mt = 0; mt < 4; ++mt)
            for (int nt = 0; nt < 4; ++nt) {
                int h  = wn * 64 + nt * 16 + c;
                int t0 = row0 + wm * 64 + mt * 16 + g * 4;
                for (int i = 0; i < 4; ++i)
                    Ko[(size_t)(t0 + i) * HH + h] = (bf16_t)acc[mt][nt][i];
            }
    } else {
        int b  = row0 >> 11;
        int tb = row0 & (TT - 1);
        for (int mt = 0; mt < 4; ++mt)
            for (int nt = 0; nt < 4; ++nt) {
                int h   = wn * 64 + nt * 16 + c;
                int tt0 = tb + wm * 64 + mt * 16 + g * 4;
                union { bf16_t h4[4]; unsigned long long u; } pk;
                for (int i = 0; i < 4; ++i) pk.h4[i] = (bf16_t)acc[mt][nt][i];
                *reinterpret_cast<unsigned long long*>(
                    Vt + ((size_t)(b * HH + h)) * TT + tt0) = pk.u;
            }
    }
}

// ---------------- flash attention (causal) ----------------
// block 256 thr = 4 waves; block handles 64 q rows (wave w: rows q0+16w..+15)
// Q pre-scaled; K [b][t][128]; V transposed [b][128][t]
__global__ __launch_bounds__(256) void attn_kernel(
    const bf16_t* __restrict__ Q, const bf16_t* __restrict__ K,
    const bf16_t* __restrict__ V, float* __restrict__ out)
{
    __shared__ __attribute__((aligned(16))) bf16_t Pl[4][16][32];
    const int tid = threadIdx.x;
    const int lane = tid & 63;
    const int wid = tid >> 6;
    const int g = lane >> 4, c = lane & 15;
    const int b = blockIdx.y;
    const int q0 = blockIdx.x * 64;
    const int wq0 = q0 + wid * 16;
    const bf16_t* Qb = Q + (size_t)b * TT * HH;
    const bf16_t* Kb = K + (size_t)b * TT * HH;
    const bf16_t* Vb = V + (size_t)b * HH * TT;
    bf16_t (*P)[32] = Pl[wid];

    bf16x8 qf[4];
    for (int kk = 0; kk < 4; ++kk)
        qf[kk] = *reinterpret_cast<const bf16x8*>(Qb + (size_t)(wq0 + c) * HH + kk * 32 + g * 8);

    f32x4 acc[8];
    for (int hb = 0; hb < 8; ++hb) acc[hb] = (f32x4)0.0f;
    float m[4], l[4];
    for (int i = 0; i < 4; ++i) { m[i] = -1e30f; l[i] = 0.0f; }

    const int kv_end = wq0 + 16;                 // causal limit for this wave
    for (int kv0 = 0; kv0 < kv_end; kv0 += 32) {
        f32x4 s0 = (f32x4)0.0f, s1 = (f32x4)0.0f;
        for (int kk = 0; kk < 4; ++kk) {
            bf16x8 k0f = *reinterpret_cast<const bf16x8*>(
                Kb + (size_t)(kv0 + c) * HH + kk * 32 + g * 8);
            bf16x8 k1f = *reinterpret_cast<const bf16x8*>(
                Kb + (size_t)(kv0 + 16 + c) * HH + kk * 32 + g * 8);
            s0 = MFMA16(qf[kk], k0f, s0);
            s1 = MFMA16(qf[kk], k1f, s1);
        }
        if (kv0 + 32 >= kv_end) {                // diagonal tile: causal mask
            for (int i = 0; i < 4; ++i) {
                int row = wq0 + g * 4 + i;
                if (kv0 + c > row)      s0[i] = -1e30f;
                if (kv0 + 16 + c > row) s1[i] = -1e30f;
            }
        }
        float pm[4];
        for (int i = 0; i < 4; ++i) pm[i] = fmaxf(s0[i], s1[i]);
        for (int off = 1; off < 16; off <<= 1)
            for (int i = 0; i < 4; ++i) pm[i] = fmaxf(pm[i], __shfl_xor(pm[i], off, 64));
        float al[4], p0[4], p1[4], ps[4];
        for (int i = 0; i < 4; ++i) {
            float mn = fmaxf(m[i], pm[i]);
            al[i] = __expf(m[i] - mn);
            m[i] = mn;
            p0[i] = __expf(s0[i] - mn);
            p1[i] = __expf(s1[i] - mn);
            ps[i] = p0[i] + p1[i];
        }
        for (int off = 1; off < 16; off <<= 1)
            for (int i = 0; i < 4; ++i) ps[i] += __shfl_xor(ps[i], off, 64);
        for (int i = 0; i < 4; ++i) l[i] = l[i] * al[i] + ps[i];
        for (int hb = 0; hb < 8; ++hb)
            for (int i = 0; i < 4; ++i) acc[hb][i] *= al[i];
        // bounce P through LDS: D-layout -> A-frag layout
        for (int i = 0; i < 4; ++i) {
            P[g * 4 + i][c]      = (bf16_t)p0[i];
            P[g * 4 + i][c + 16] = (bf16_t)p1[i];
        }
        __builtin_amdgcn_wave_barrier();
        asm volatile("s_waitcnt lgkmcnt(0)" ::: "memory");
        __builtin_amdgcn_sched_barrier(0);
        bf16x8 pa = *reinterpret_cast<const bf16x8*>(&P[c][g * 8]);
        for (int hb = 0; hb < 8; ++hb) {
            bf16x8 vf = *reinterpret_cast<const bf16x8*>(
                Vb + (size_t)(hb * 16 + c) * TT + kv0 + g * 8);
            acc[hb] = MFMA16(pa, vf, acc[hb]);
        }
        __builtin_amdgcn_wave_barrier();
    }

    float inv[4];
    for (int i = 0; i < 4; ++i) inv[i] = 1.0f / l[i];
    for (int hb = 0; hb < 8; ++hb)
        for (int i = 0; i < 4; ++i)
            out[((size_t)b * TT + wq0 + g * 4 + i) * HH + hb * 16 + c] =
                acc[hb][i] * inv[i];
}

extern "C" void kernel_launch(void* const* d_in, const int* in_sizes, int n_in,
                              void* d_out, int out_size, void* d_ws, size_t ws_size,
                              hipStream_t stream)
{
    const float* x  = (const float*)d_in[0];
    const float* Wq = (const float*)d_in[1];
    const float* Wk = (const float*)d_in[2];
    const float* Wv = (const float*)d_in[3];

    char* ws = (char*)d_ws;
    bf16_t* Wt = (bf16_t*)ws;                          // 3*128*1024*2 = 768 KB
    bf16_t* Qb = (bf16_t*)(ws + (1u << 20));           // 4 MB
    bf16_t* Kb = (bf16_t*)(ws + (1u << 20) + (4u << 20));
    bf16_t* Vt = (bf16_t*)(ws + (1u << 20) + (8u << 20));

    prep_w_kernel<<<1536, 256, 0, stream>>>(Wq, Wk, Wv, Wt);
    qkv_kernel<<<dim3(128, 3), 256, 0, stream>>>(x, Wt, Qb, Kb, Vt);
    attn_kernel<<<dim3(32, 8), 256, 0, stream>>>(Qb, Kb, Vt, (float*)d_out);
}

// Round 2
// 169.910 us; speedup vs baseline: 1.0864x; 1.0864x over previous
//
#include <hip/hip_runtime.h>
#include <hip/hip_bf16.h>

typedef __bf16 bf16_t;
typedef bf16_t bf16x8 __attribute__((ext_vector_type(8)));
typedef float f32x4 __attribute__((ext_vector_type(4)));

#define MFMA16(a, b, c) __builtin_amdgcn_mfma_f32_16x16x32_bf16((a), (b), (c), 0, 0, 0)

// B=8, T=2048, E=1024, H=128
#define TT 2048
#define EE 1024
#define HH 128
#define UNITS_PER_B 576   // sum over 128 qtiles of ceil((qt+1)/16)

// ---------------- prep: Wt[w][n][k] = W[w][k][n], f32 -> bf16 ----------------
__global__ __launch_bounds__(256) void prep_w_kernel(
    const float* __restrict__ Wq, const float* __restrict__ Wk,
    const float* __restrict__ Wv, bf16_t* __restrict__ Wt)
{
    int idx = blockIdx.x * 256 + threadIdx.x;   // 0 .. 3*131072-1
    int w = idx >> 17;
    int r = idx & 131071;                        // n*1024 + k
    int n = r >> 10, k = r & 1023;
    const float* W = (w == 0) ? Wq : (w == 1) ? Wk : Wv;
    Wt[idx] = (bf16_t)W[k * HH + n];
}

// ---------------- QKV GEMM: [16384 x 1024] x [1024 x 128] ----------------
__global__ __launch_bounds__(256) void qkv_kernel(
    const float* __restrict__ x, const bf16_t* __restrict__ Wt,
    bf16_t* __restrict__ Q, bf16_t* __restrict__ Ko, bf16_t* __restrict__ Vt)
{
    __shared__ __attribute__((aligned(16))) bf16_t As[128][40];
    const int row0  = blockIdx.x * 128;
    const int which = blockIdx.y;                 // 0=Q 1=K 2=V
    const bf16_t* Wp = Wt + (size_t)which * (HH * EE);
    const int tid = threadIdx.x;
    const int lane = tid & 63;
    const int wid = tid >> 6;
    const int wm = wid >> 1, wn = wid & 1;
    const int g = lane >> 4, c = lane & 15;

    f32x4 acc[4][4];
    for (int i = 0; i < 4; ++i)
        for (int j = 0; j < 4; ++j) acc[i][j] = (f32x4)0.0f;

    for (int k0 = 0; k0 < EE; k0 += 32) {
        __syncthreads();
        for (int j = 0; j < 4; ++j) {
            int s = tid + j * 256;
            int r = s >> 3, c4 = s & 7;
            float4 f = *reinterpret_cast<const float4*>(
                x + (size_t)(row0 + r) * EE + k0 + c4 * 4);
            union { bf16_t h[4]; unsigned long long u; } pk;
            pk.h[0] = (bf16_t)f.x; pk.h[1] = (bf16_t)f.y;
            pk.h[2] = (bf16_t)f.z; pk.h[3] = (bf16_t)f.w;
            *reinterpret_cast<unsigned long long*>(&As[r][c4 * 4]) = pk.u;
        }
        __syncthreads();
        bf16x8 bfr[4];
        for (int nt = 0; nt < 4; ++nt)
            bfr[nt] = *reinterpret_cast<const bf16x8*>(
                Wp + (size_t)(wn * 64 + nt * 16 + c) * EE + k0 + g * 8);
        for (int mt = 0; mt < 4; ++mt) {
            bf16x8 af = *reinterpret_cast<const bf16x8*>(&As[wm * 64 + mt * 16 + c][g * 8]);
            for (int nt = 0; nt < 4; ++nt)
                acc[mt][nt] = MFMA16(af, bfr[nt], acc[mt][nt]);
        }
    }

    if (which == 0) {
        const float sc = 0.08838834764831845f;   // 1/sqrt(128)
        for (int mt = 0; mt < 4; ++mt)
            for (int nt = 0; nt < 4; ++nt) {
                int h  = wn * 64 + nt * 16 + c;
                int t0 = row0 + wm * 64 + mt * 16 + g * 4;
                for (int i = 0; i < 4; ++i)
                    Q[(size_t)(t0 + i) * HH + h] = (bf16_t)(acc[mt][nt][i] * sc);
            }
    } else if (which == 1) {
        for (int mt = 0; mt < 4; ++mt)
            for (int nt = 0; nt < 4; ++nt) {
                int h  = wn * 64 + nt * 16 + c;
                int t0 = row0 + wm * 64 + mt * 16 + g * 4;
                for (int i = 0; i < 4; ++i)
                    Ko[(size_t)(t0 + i) * HH + h] = (bf16_t)acc[mt][nt][i];
            }
    } else {
        int b  = row0 >> 11;
        int tb = row0 & (TT - 1);
        for (int mt = 0; mt < 4; ++mt)
            for (int nt = 0; nt < 4; ++nt) {
                int h   = wn * 64 + nt * 16 + c;
                int tt0 = tb + wm * 64 + mt * 16 + g * 4;
                union { bf16_t h4[4]; unsigned long long u; } pk;
                for (int i = 0; i < 4; ++i) pk.h4[i] = (bf16_t)acc[mt][nt][i];
                *reinterpret_cast<unsigned long long*>(
                    Vt + ((size_t)(b * HH + h)) * TT + tt0) = pk.u;
            }
    }
}

// ---------------- flash attention, split-KV partials ----------------
// one wave (64 thr) per unit = (b, qtile16, kvchunk256).
// outputs: Pacc[unit][16][128] bf16 (unnormalized), Pml[unit][32] f32 (m,l)
__global__ __launch_bounds__(64) void attn_kernel(
    const bf16_t* __restrict__ Q, const bf16_t* __restrict__ K,
    const bf16_t* __restrict__ V, bf16_t* __restrict__ Pacc,
    float* __restrict__ Pml)
{
    __shared__ __attribute__((aligned(16))) bf16_t P[16][32];
    const int lane = threadIdx.x;
    const int g = lane >> 4, c = lane & 15;

    // decode unit id -> (b, qtile, chunk)
    const int gid = blockIdx.x;
    const int b = gid / UNITS_PER_B;
    const int u = gid - b * UNITS_PER_B;
    int k = 0;
    while (8 * (k + 1) * (k + 2) <= u) ++k;      // k in 0..7
    const int r  = u - 8 * k * (k + 1);
    const int qt = 16 * k + r / (k + 1);
    const int ch = r - (r / (k + 1)) * (k + 1);
    const int q0 = qt * 16;
    const int kv_lo = ch * 256;
    const int kv_hi_full = kv_lo + 256;
    const int kv_hi = (kv_hi_full < q0 + 16) ? kv_hi_full : (q0 + 16);

    const bf16_t* Qb = Q + (size_t)b * TT * HH;
    const bf16_t* Kb = K + (size_t)b * TT * HH;
    const bf16_t* Vb = V + (size_t)b * HH * TT;

    bf16x8 qf[4];
    for (int kk = 0; kk < 4; ++kk)
        qf[kk] = *reinterpret_cast<const bf16x8*>(
            Qb + (size_t)(q0 + c) * HH + kk * 32 + g * 8);

    f32x4 acc[8];
    for (int hb = 0; hb < 8; ++hb) acc[hb] = (f32x4)0.0f;
    float m[4], l[4];
    for (int i = 0; i < 4; ++i) { m[i] = -1e30f; l[i] = 0.0f; }

    for (int kv0 = kv_lo; kv0 < kv_hi; kv0 += 32) {
        // K loads (independent) + V loads hoisted above softmax
        bf16x8 k0f[4], k1f[4];
        for (int kk = 0; kk < 4; ++kk) {
            k0f[kk] = *reinterpret_cast<const bf16x8*>(
                Kb + (size_t)(kv0 + c) * HH + kk * 32 + g * 8);
            k1f[kk] = *reinterpret_cast<const bf16x8*>(
                Kb + (size_t)(kv0 + 16 + c) * HH + kk * 32 + g * 8);
        }
        bf16x8 vf[8];
        for (int hb = 0; hb < 8; ++hb)
            vf[hb] = *reinterpret_cast<const bf16x8*>(
                Vb + (size_t)(hb * 16 + c) * TT + kv0 + g * 8);

        f32x4 s0 = (f32x4)0.0f, s1 = (f32x4)0.0f;
        for (int kk = 0; kk < 4; ++kk) {
            s0 = MFMA16(qf[kk], k0f[kk], s0);
            s1 = MFMA16(qf[kk], k1f[kk], s1);
        }
        if (kv0 + 32 >= kv_hi) {                 // diagonal / partial tile
            for (int i = 0; i < 4; ++i) {
                int row = q0 + g * 4 + i;
                if (kv0 + c > row)      s0[i] = -1e30f;
                if (kv0 + 16 + c > row) s1[i] = -1e30f;
            }
        }
        float pm[4];
        for (int i = 0; i < 4; ++i) pm[i] = fmaxf(s0[i], s1[i]);
        for (int off = 1; off < 16; off <<= 1)
            for (int i = 0; i < 4; ++i) pm[i] = fmaxf(pm[i], __shfl_xor(pm[i], off, 64));
        float al[4], p0[4], p1[4], ps[4];
        for (int i = 0; i < 4; ++i) {
            float mn = fmaxf(m[i], pm[i]);
            al[i] = __expf(m[i] - mn);
            m[i] = mn;
            p0[i] = __expf(s0[i] - mn);
            p1[i] = __expf(s1[i] - mn);
            ps[i] = p0[i] + p1[i];
        }
        for (int off = 1; off < 16; off <<= 1)
            for (int i = 0; i < 4; ++i) ps[i] += __shfl_xor(ps[i], off, 64);
        for (int i = 0; i < 4; ++i) l[i] = l[i] * al[i] + ps[i];
        for (int hb = 0; hb < 8; ++hb)
            for (int i = 0; i < 4; ++i) acc[hb][i] *= al[i];
        // bounce P through LDS: D-layout -> A-frag layout
        for (int i = 0; i < 4; ++i) {
            P[g * 4 + i][c]      = (bf16_t)p0[i];
            P[g * 4 + i][c + 16] = (bf16_t)p1[i];
        }
        __builtin_amdgcn_wave_barrier();
        asm volatile("s_waitcnt lgkmcnt(0)" ::: "memory");
        __builtin_amdgcn_sched_barrier(0);
        bf16x8 pa = *reinterpret_cast<const bf16x8*>(&P[c][g * 8]);
        for (int hb = 0; hb < 8; ++hb)
            acc[hb] = MFMA16(pa, vf[hb], acc[hb]);
        __builtin_amdgcn_wave_barrier();
    }

    // store partial stats + unnormalized acc
    if (c == 0) {
        for (int i = 0; i < 4; ++i) {
            Pml[(size_t)gid * 32 + g * 4 + i]      = m[i];
            Pml[(size_t)gid * 32 + 16 + g * 4 + i] = l[i];
        }
    }
    bf16_t* pa_out = Pacc + (size_t)gid * (16 * 128);
    for (int hb = 0; hb < 8; ++hb)
        for (int i = 0; i < 4; ++i)
            pa_out[(g * 4 + i) * 128 + hb * 16 + c] = (bf16_t)acc[hb][i];
}

// ---------------- combine partials ----------------
// block per (qtile, b), 128 threads (one per head col)
__global__ __launch_bounds__(128) void combine_kernel(
    const bf16_t* __restrict__ Pacc, const float* __restrict__ Pml,
    float* __restrict__ out)
{
    __shared__ float w[8][16];
    const int qt = blockIdx.x;                   // 0..127
    const int b  = blockIdx.y;
    const int k  = qt >> 4;
    const int base  = b * UNITS_PER_B + 8 * k * (k + 1) + (qt & 15) * (k + 1);
    const int count = k + 1;
    const int tid = threadIdx.x;

    if (tid < 16) {
        const int row = tid;
        float M = -1e30f;
        for (int cu = 0; cu < count; ++cu)
            M = fmaxf(M, Pml[(size_t)(base + cu) * 32 + row]);
        float L = 0.0f;
        for (int cu = 0; cu < count; ++cu)
            L += __expf(Pml[(size_t)(base + cu) * 32 + row] - M) *
                 Pml[(size_t)(base + cu) * 32 + 16 + row];
        float invL = 1.0f / L;
        for (int cu = 0; cu < count; ++cu)
            w[cu][row] = __expf(Pml[(size_t)(base + cu) * 32 + row] - M) * invL;
    }
    __syncthreads();

    const int col = tid;                         // 0..127
    const int q0 = qt * 16;
    for (int row = 0; row < 16; ++row) {
        float s = 0.0f;
        for (int cu = 0; cu < count; ++cu)
            s += w[cu][row] *
                 (float)Pacc[(size_t)(base + cu) * 2048 + row * 128 + col];
        out[((size_t)b * TT + q0 + row) * HH + col] = s;
    }
}

extern "C" void kernel_launch(void* const* d_in, const int* in_sizes, int n_in,
                              void* d_out, int out_size, void* d_ws, size_t ws_size,
                              hipStream_t stream)
{
    const float* x  = (const float*)d_in[0];
    const float* Wq = (const float*)d_in[1];
    const float* Wk = (const float*)d_in[2];
    const float* Wv = (const float*)d_in[3];

    char* ws = (char*)d_ws;
    bf16_t* Wt   = (bf16_t*)ws;                       // 768 KB
    bf16_t* Qb   = (bf16_t*)(ws + (1u  << 20));       // 4 MB
    bf16_t* Kb   = (bf16_t*)(ws + (5u  << 20));       // 4 MB
    bf16_t* Vt   = (bf16_t*)(ws + (9u  << 20));       // 4 MB
    bf16_t* Pacc = (bf16_t*)(ws + (13u << 20));       // 4608*4096 B = 18.9 MB
    float*  Pml  = (float*) (ws + (32u << 20));       // 4608*128 B  = 0.6 MB

    prep_w_kernel<<<1536, 256, 0, stream>>>(Wq, Wk, Wv, Wt);
    qkv_kernel<<<dim3(128, 3), 256, 0, stream>>>(x, Wt, Qb, Kb, Vt);
    attn_kernel<<<8 * UNITS_PER_B, 64, 0, stream>>>(Qb, Kb, Vt, Pacc, Pml);
    combine_kernel<<<dim3(128, 8), 128, 0, stream>>>(Pacc, Pml, (float*)d_out);
}